// Round 4
// baseline (31027.017 us; speedup 1.0000x reference)
//
#include <hip/hip_runtime.h>
#include <hip/hip_bf16.h>
#include <stdint.h>

// LSTM_48601849922171 — 2-layer LSTM (B=8, T=2048, D_IN=256, H=512), fp32 I/O,
// bf16 MFMA compute.
//
// Round 4: sentinel-sync (Persistent-RNN style). h buffers are pre-filled with
// 0xFF (bf16 NaN); h = ot*relu(c) is always finite & >= 0, so data can never
// equal the sentinel. Producers store h via relaxed agent atomics (sc0 sc1 ->
// coherent L3); consumers SPIN ON THE DATA WORDS THEMSELVES until
// != sentinel — the successful poll load IS the MFMA operand. No flags, no
// __syncthreads, no fences, no producer-side drain in the recurrence loop.
//
// Pipeline:
//   cvt x4 (weights fp32->bf16) ; memset 0xFF h bufs ; K1 gemm_proj wx0 ;
//   K2 lstm_rec L0 ; K3 gemm_proj wx1 ; K4 lstm_rec L1 -> d_out.
//
// Workspace (~135 MB):
//   0:        Wb0 1MB | 1MB: Ub0 2MB | 3MB: Wb1 2MB | 5MB: Ub1 2MB
//   7340032:  wx  [2048][8][2048] bf16 (64MB, reused both layers)
//   74448896: h1s [2048][16][512] bf16 (32MB; rows 8..15 pad)
//   108003328:h2s [2048][16][512] bf16 (32MB)

typedef __hip_bfloat16 bf16;
typedef float  floatx4 __attribute__((ext_vector_type(4)));
typedef short  short8  __attribute__((ext_vector_type(8)));
typedef short  short4v __attribute__((ext_vector_type(4)));
typedef unsigned long long u64;

#define T_STEPS  2048
#define NB_REC   16
#define SENT64   0xFFFFFFFFFFFFFFFFull
#define HH_OFF   8388608   // 8*2048*512
#define CC_OFF   8396800   // HH_OFF + 2*8*512

static __device__ __forceinline__ float bs2f(short s) {
  union { unsigned int u; float f; } c;
  c.u = ((unsigned int)(unsigned short)s) << 16;
  return c.f;
}
static __device__ __forceinline__ short f2bs(float x) {
  union { bf16 h; short s; } u;
  u.h = __float2bfloat16(x);
  return u.s;
}
static __device__ __forceinline__ float sigm(float x) {
  x = fminf(fmaxf(x, -30.f), 30.f);
  return 1.f / (1.f + __expf(-x));
}
static __device__ __forceinline__ float tanhf_(float x) {
  x = fminf(fmaxf(x, -15.f), 15.f);
  float e = __expf(2.f * x);
  return (e - 1.f) / (e + 1.f);
}
static __device__ __forceinline__ floatx4 mfma_bf16(short8 a, short8 b, floatx4 c) {
  return __builtin_amdgcn_mfma_f32_16x16x32_bf16(a, b, c, 0, 0, 0);
}
static __device__ __forceinline__ u64 cload(const bf16* p) {   // coherent 8B load
  return __hip_atomic_load(reinterpret_cast<const u64*>(p),
                           __ATOMIC_RELAXED, __HIP_MEMORY_SCOPE_AGENT);
}

// fp32 -> bf16 elementwise (n multiple of 4)
__global__ __launch_bounds__(256)
void cvt_f32_bf16(const float* __restrict__ src, bf16* __restrict__ dst, int n) {
  int i = (blockIdx.x * 256 + threadIdx.x) * 4;
  if (i < n) {
    floatx4 v = *reinterpret_cast<const floatx4*>(src + i);
    short4v o;
    #pragma unroll
    for (int r = 0; r < 4; ++r) o[r] = f2bs(v[r]);
    *reinterpret_cast<short4v*>(dst + i) = o;
  }
}

// ---------------------------------------------------------------------------
// out[m][n] = sum_k A[m][k]*W[n][k] + bias[n], m = t*8+b, out [16384][2048] bf16.
// A row base = (m&7)*strideB + (m>>3)*strideT. Af fp32 xor Ab bf16. W bf16 [n][K].
// Block 256 thr; wave tile M=16 x N=64; grid (1024, 8).
// ---------------------------------------------------------------------------
__global__ __launch_bounds__(256)
void gemm_proj(const float* __restrict__ Af, const bf16* __restrict__ Ab,
               const bf16* __restrict__ W, const float* __restrict__ bias,
               bf16* __restrict__ out, int K, int strideB, int strideT)
{
  const int lane  = threadIdx.x & 63;
  const int wave  = threadIdx.x >> 6;
  const int q     = lane >> 4;
  const int c     = lane & 15;
  const int mtile = blockIdx.x;
  const int nbase = blockIdx.y * 256 + wave * 64;
  const int m     = mtile * 16 + c;

  const long abase = (long)(m & 7) * strideB + (long)(m >> 3) * strideT + q * 8;
  const bf16* W0 = W + (long)(nbase +  0 + c) * K + q * 8;
  const bf16* W1 = W + (long)(nbase + 16 + c) * K + q * 8;
  const bf16* W2 = W + (long)(nbase + 32 + c) * K + q * 8;
  const bf16* W3 = W + (long)(nbase + 48 + c) * K + q * 8;

  floatx4 acc0 = {0.f, 0.f, 0.f, 0.f};
  floatx4 acc1 = acc0, acc2 = acc0, acc3 = acc0;
  const int nk = K >> 5;
  for (int kt = 0; kt < nk; ++kt) {
    short8 a;
    if (Af != nullptr) {
      floatx4 lo = *reinterpret_cast<const floatx4*>(Af + abase + kt * 32);
      floatx4 hi = *reinterpret_cast<const floatx4*>(Af + abase + kt * 32 + 4);
      #pragma unroll
      for (int r = 0; r < 4; ++r) { a[r] = f2bs(lo[r]); a[4 + r] = f2bs(hi[r]); }
    } else {
      a = *reinterpret_cast<const short8*>(Ab + abase + kt * 32);
    }
    short8 b0 = *reinterpret_cast<const short8*>(W0 + kt * 32);
    short8 b1 = *reinterpret_cast<const short8*>(W1 + kt * 32);
    short8 b2 = *reinterpret_cast<const short8*>(W2 + kt * 32);
    short8 b3 = *reinterpret_cast<const short8*>(W3 + kt * 32);
    acc0 = mfma_bf16(a, b0, acc0);
    acc1 = mfma_bf16(a, b1, acc1);
    acc2 = mfma_bf16(a, b2, acc2);
    acc3 = mfma_bf16(a, b3, acc3);
  }

  floatx4 accs[4] = {acc0, acc1, acc2, acc3};
  #pragma unroll
  for (int nt = 0; nt < 4; ++nt) {
    const int n = nbase + nt * 16 + c;
    const float bv = bias[n];
    #pragma unroll
    for (int r = 0; r < 4; ++r) {
      const int mrow = mtile * 16 + q * 4 + r;
      out[(long)mrow * 2048 + n] = __float2bfloat16(accs[nt][r] + bv);
    }
  }
}

// ---------------------------------------------------------------------------
// Persistent recurrence, 16 blocks x 256 thr, barrier-free + flag-free.
// Wave owns 8 h-cols: A-tile0 rows {i,f}, A-tile1 rows {g,o};
// D[m=q*4+r][n=b]: f/o rows in quads 2,3 paired via shfl_xor(.,32).
// Sync = sentinel-poll directly on the h data words (coherent sc0sc1).
// ---------------------------------------------------------------------------
__global__ __launch_bounds__(256, 1)
void lstm_rec(const bf16* __restrict__ wx, const bf16* __restrict__ U,
              const float* __restrict__ ub, bf16* __restrict__ hseq,
              float* __restrict__ hout, float* __restrict__ hh,
              float* __restrict__ cc)
{
  const int lane  = threadIdx.x & 63;
  const int wave  = threadIdx.x >> 6;
  const int q     = lane >> 4;
  const int b     = lane & 15;
  const int jbase = blockIdx.x * 32 + wave * 8;

  // Preload recurrent weights as A-frags (2 M-tiles x 16 k-frags).
  short8 a0[16], a1[16];
  {
    const int row0 = (b < 8) ? (jbase + b) : (512 + jbase + b - 8);           // i | f
    const int row1 = (b < 8) ? (1024 + jbase + b) : (1536 + jbase + b - 8);   // g | o
    const bf16* U0 = U + (long)row0 * 512 + q * 8;
    const bf16* U1 = U + (long)row1 * 512 + q * 8;
    #pragma unroll
    for (int kt = 0; kt < 16; ++kt) {
      a0[kt] = *reinterpret_cast<const short8*>(U0 + kt * 32);
      a1[kt] = *reinterpret_cast<const short8*>(U1 + kt * 32);
    }
  }

  const int jj = jbase + (q & 1) * 4;   // epilogue j-range (meaningful for q<2)
  float ubi[4], ubf[4], ubg[4], ubo[4];
  #pragma unroll
  for (int r = 0; r < 4; ++r) {
    ubi[r] = ub[        jj + r];
    ubf[r] = ub[ 512 + jj + r];
    ubg[r] = ub[1024 + jj + r];
    ubo[r] = ub[1536 + jj + r];
  }

  float cst[4] = {0.f, 0.f, 0.f, 0.f};

  for (int t = 0; t < T_STEPS; ++t) {
    // Prefetch this step's input projection (plain cached loads; producer was
    // a previous dispatch, so kernel-start acquire covers coherence).
    const bf16* wxp = wx + (long)t * 16384 + (b & 7) * 2048 + jj;
    short4v vi = *reinterpret_cast<const short4v*>(wxp);
    short4v vf = *reinterpret_cast<const short4v*>(wxp + 512);
    short4v vg = *reinterpret_cast<const short4v*>(wxp + 1024);
    short4v vo = *reinterpret_cast<const short4v*>(wxp + 1536);

    floatx4 acc0 = {0.f, 0.f, 0.f, 0.f};
    floatx4 acc1 = {0.f, 0.f, 0.f, 0.f};

    if (t > 0) {
      const bf16* hp = hseq + (long)(t - 1) * 8192 + b * 512 + q * 8;
      // Two chunks of 8 k-frags: poll 16 8B words until != sentinel, then MFMA.
      #pragma unroll
      for (int ch = 0; ch < 2; ++ch) {
        u64 hw[16];
        #pragma unroll
        for (int i = 0; i < 16; ++i) hw[i] = SENT64;
        int any, guard = 0;
        do {
          any = 0;
          #pragma unroll
          for (int k8 = 0; k8 < 8; ++k8) {
            const bf16* p = hp + (ch * 8 + k8) * 32;
            if (hw[k8 * 2] == SENT64) {
              u64 v = cload(p);
              hw[k8 * 2] = v;
              if (v == SENT64) any = 1;
            }
            if (hw[k8 * 2 + 1] == SENT64) {
              u64 v = cload(p + 4);
              hw[k8 * 2 + 1] = v;
              if (v == SENT64) any = 1;
            }
          }
        } while (__any(any) && ++guard < (1 << 18));
        #pragma unroll
        for (int k8 = 0; k8 < 8; ++k8) {
          union { u64 u[2]; short8 v; } pk;
          pk.u[0] = hw[k8 * 2];
          pk.u[1] = hw[k8 * 2 + 1];
          acc0 = mfma_bf16(a0[ch * 8 + k8], pk.v, acc0);
          acc1 = mfma_bf16(a1[ch * 8 + k8], pk.v, acc1);
        }
      }
    }

    float wxi[4], wxf[4], wxg[4], wxo[4];
    #pragma unroll
    for (int r = 0; r < 4; ++r) {
      wxi[r] = bs2f(vi[r]); wxf[r] = bs2f(vf[r]);
      wxg[r] = bs2f(vg[r]); wxo[r] = bs2f(vo[r]);
    }

    // Pair i<->f and g<->o across lane^32 (all lanes execute the shfl).
    float fsh[4], osh[4];
    #pragma unroll
    for (int r = 0; r < 4; ++r) {
      fsh[r] = __shfl_xor(acc0[r], 32, 64);
      osh[r] = __shfl_xor(acc1[r], 32, 64);
    }

    if (q < 2) {
      short4v hp4;
      floatx4  hf4, cf4;
      #pragma unroll
      for (int r = 0; r < 4; ++r) {
        const float pi = acc0[r] + wxi[r] + ubi[r];
        const float pf = fsh[r]  + wxf[r] + ubf[r];
        const float pg = acc1[r] + wxg[r] + ubg[r];
        const float po = osh[r]  + wxo[r] + ubo[r];
        const float it = sigm(pi);
        const float ft = sigm(pf);
        const float gt = tanhf_(pg);
        const float ot = sigm(po);
        const float cv = ft * cst[r] + it * gt;
        cst[r] = cv;
        const float hv = ot * fmaxf(cv, 0.f);   // custom nonlinearity: relu(c)
        hf4[r] = hv;
        cf4[r] = cv;
        hp4[r] = f2bs(hv);
      }
      // h -> coherent point FIRST (this is the release: data == flag).
      union { short4v v; u64 u; } pk; pk.v = hp4;
      __hip_atomic_store(
          reinterpret_cast<u64*>(hseq + (long)t * 8192 + b * 512 + jj),
          pk.u, __ATOMIC_RELAXED, __HIP_MEMORY_SCOPE_AGENT);
      // Fire-and-forget outputs (nothing waits on these until kernel end).
      if (hout != nullptr && b < 8) {          // layer-1: h2 -> d_out fp32
        *reinterpret_cast<floatx4*>(hout + (long)b * 1048576 + (long)t * 512 + jj) = hf4;
      }
      if (t == T_STEPS - 1 && b < 8) {         // final h/c states fp32
        *reinterpret_cast<floatx4*>(hh + b * 512 + jj) = hf4;
        *reinterpret_cast<floatx4*>(cc + b * 512 + jj) = cf4;
      }
    }
    // No barrier, no flag — next iteration's polls self-synchronize.
  }
}

extern "C" void kernel_launch(void* const* d_in, const int* in_sizes, int n_in,
                              void* d_out, int out_size, void* d_ws, size_t ws_size,
                              hipStream_t stream) {
  (void)in_sizes; (void)n_in; (void)out_size; (void)ws_size;
  const float* x   = (const float*)d_in[0];
  const float* w0w = (const float*)d_in[1];
  const float* w0b = (const float*)d_in[2];
  const float* u0w = (const float*)d_in[3];
  const float* u0b = (const float*)d_in[4];
  const float* w1w = (const float*)d_in[5];
  const float* w1b = (const float*)d_in[6];
  const float* u1w = (const float*)d_in[7];
  const float* u1b = (const float*)d_in[8];
  float* out = (float*)d_out;

  char* ws = (char*)d_ws;
  bf16* Wb0 = (bf16*)(ws + 0);
  bf16* Ub0 = (bf16*)(ws + (size_t)1048576);
  bf16* Wb1 = (bf16*)(ws + (size_t)3145728);
  bf16* Ub1 = (bf16*)(ws + (size_t)5242880);
  bf16* wx  = (bf16*)(ws + (size_t)7340032);
  bf16* h1s = (bf16*)(ws + (size_t)74448896);
  bf16* h2s = (bf16*)(ws + (size_t)108003328);

  // Sentinel-fill both h buffers (64 MB of 0xFF = bf16 NaN pairs).
  hipMemsetAsync(ws + (size_t)74448896, 0xFF, (size_t)67108864, stream);

  // Weight conversions fp32 -> bf16.
  cvt_f32_bf16<<<512,  256, 0, stream>>>(w0w, Wb0, 524288);
  cvt_f32_bf16<<<1024, 256, 0, stream>>>(u0w, Ub0, 1048576);
  cvt_f32_bf16<<<1024, 256, 0, stream>>>(w1w, Wb1, 1048576);
  cvt_f32_bf16<<<1024, 256, 0, stream>>>(u1w, Ub1, 1048576);

  dim3 gg(1024, 8, 1);
  // Layer 0 input projection: A = x[b][t][d] fp32.
  gemm_proj<<<gg, 256, 0, stream>>>(x, nullptr, Wb0, w0b, wx, 256, 2048 * 256, 256);
  // Layer 0 recurrence.
  lstm_rec<<<NB_REC, 256, 0, stream>>>(wx, Ub0, u0b, h1s, nullptr,
                                       out + HH_OFF, out + CC_OFF);
  // Layer 1 input projection: A = h1s[t][16][512] bf16.
  gemm_proj<<<gg, 256, 0, stream>>>(nullptr, h1s, Wb1, w1b, wx, 512, 512, 8192);
  // Layer 1 recurrence (writes h2 fp32 to d_out).
  lstm_rec<<<NB_REC, 256, 0, stream>>>(wx, Ub1, u1b, h2s, out,
                                       out + HH_OFF + 4096, out + CC_OFF + 4096);
}

// Round 5
// 21620.332 us; speedup vs baseline: 1.4351x; 1.4351x over previous
//
#include <hip/hip_runtime.h>
#include <hip/hip_bf16.h>
#include <stdint.h>

// LSTM_48601849922171 — 2-layer LSTM (B=8, T=2048, D_IN=256, H=512), fp32 I/O,
// bf16 MFMA compute.
//
// Round 5: wave-per-block recurrence (64 blocks x 64 thr) — no __syncthreads
// anywhere in the recurrence. Flag-based sync (R3 style, which beat R4's
// data-sentinel polling): producer stores h via relaxed agent atomics
// (sc0 sc1 -> coherent IC), drains with inline s_waitcnt vmcnt(0), lane 0
// publishes a per-step per-block flag; consumers poll 64 flags (one per lane,
// single coalesced 4B coherent load) with __all, then bulk-load h once.
//
// Pipeline:
//   cvt x4 (weights fp32->bf16) ; K1 gemm_proj wx0 ; K2 lstm_rec L0 ;
//   K3 gemm_proj wx1 ; K4 lstm_rec L1 -> d_out.
//
// Workspace (~136 MB):
//   0:        flags0 [2048][64] u32 (512KB, memset 0)
//   524288:   flags1 (512KB)
//   1048576:  Wb0 1MB | 2MB: Ub0 2MB | 4MB: Wb1 2MB | 6MB: Ub1 2MB
//   8388608:  wx  [2048][8][2048] bf16 (64MB, reused both layers)
//   75497472: h1s [2048][16][512] bf16 (32MB; rows 8..15 pad, all rows written)
//   109051904:h2s [2048][16][512] bf16 (32MB)

typedef __hip_bfloat16 bf16;
typedef float  floatx4 __attribute__((ext_vector_type(4)));
typedef short  short8  __attribute__((ext_vector_type(8)));
typedef short  short4v __attribute__((ext_vector_type(4)));
typedef unsigned long long u64;

#define T_STEPS  2048
#define NB_REC   64
#define HH_OFF   8388608   // 8*2048*512
#define CC_OFF   8396800   // HH_OFF + 2*8*512

static __device__ __forceinline__ float bs2f(short s) {
  union { unsigned int u; float f; } c;
  c.u = ((unsigned int)(unsigned short)s) << 16;
  return c.f;
}
static __device__ __forceinline__ short f2bs(float x) {
  union { bf16 h; short s; } u;
  u.h = __float2bfloat16(x);
  return u.s;
}
static __device__ __forceinline__ float sigm(float x) {
  x = fminf(fmaxf(x, -30.f), 30.f);
  return 1.f / (1.f + __expf(-x));
}
static __device__ __forceinline__ float tanhf_(float x) {
  x = fminf(fmaxf(x, -15.f), 15.f);
  float e = __expf(2.f * x);
  return (e - 1.f) / (e + 1.f);
}
static __device__ __forceinline__ floatx4 mfma_bf16(short8 a, short8 b, floatx4 c) {
  return __builtin_amdgcn_mfma_f32_16x16x32_bf16(a, b, c, 0, 0, 0);
}
static __device__ __forceinline__ u64 cload(const bf16* p) {   // coherent 8B load
  return __hip_atomic_load(reinterpret_cast<const u64*>(p),
                           __ATOMIC_RELAXED, __HIP_MEMORY_SCOPE_AGENT);
}

// fp32 -> bf16 elementwise (n multiple of 4)
__global__ __launch_bounds__(256)
void cvt_f32_bf16(const float* __restrict__ src, bf16* __restrict__ dst, int n) {
  int i = (blockIdx.x * 256 + threadIdx.x) * 4;
  if (i < n) {
    floatx4 v = *reinterpret_cast<const floatx4*>(src + i);
    short4v o;
    #pragma unroll
    for (int r = 0; r < 4; ++r) o[r] = f2bs(v[r]);
    *reinterpret_cast<short4v*>(dst + i) = o;
  }
}

// ---------------------------------------------------------------------------
// out[m][n] = sum_k A[m][k]*W[n][k] + bias[n], m = t*8+b, out [16384][2048] bf16.
// A row base = (m&7)*strideB + (m>>3)*strideT. Af fp32 xor Ab bf16. W bf16 [n][K].
// Block 256 thr; wave tile M=16 x N=64; grid (1024, 8).
// ---------------------------------------------------------------------------
__global__ __launch_bounds__(256)
void gemm_proj(const float* __restrict__ Af, const bf16* __restrict__ Ab,
               const bf16* __restrict__ W, const float* __restrict__ bias,
               bf16* __restrict__ out, int K, int strideB, int strideT)
{
  const int lane  = threadIdx.x & 63;
  const int wave  = threadIdx.x >> 6;
  const int q     = lane >> 4;
  const int c     = lane & 15;
  const int mtile = blockIdx.x;
  const int nbase = blockIdx.y * 256 + wave * 64;
  const int m     = mtile * 16 + c;

  const long abase = (long)(m & 7) * strideB + (long)(m >> 3) * strideT + q * 8;
  const bf16* W0 = W + (long)(nbase +  0 + c) * K + q * 8;
  const bf16* W1 = W + (long)(nbase + 16 + c) * K + q * 8;
  const bf16* W2 = W + (long)(nbase + 32 + c) * K + q * 8;
  const bf16* W3 = W + (long)(nbase + 48 + c) * K + q * 8;

  floatx4 acc0 = {0.f, 0.f, 0.f, 0.f};
  floatx4 acc1 = acc0, acc2 = acc0, acc3 = acc0;
  const int nk = K >> 5;
  for (int kt = 0; kt < nk; ++kt) {
    short8 a;
    if (Af != nullptr) {
      floatx4 lo = *reinterpret_cast<const floatx4*>(Af + abase + kt * 32);
      floatx4 hi = *reinterpret_cast<const floatx4*>(Af + abase + kt * 32 + 4);
      #pragma unroll
      for (int r = 0; r < 4; ++r) { a[r] = f2bs(lo[r]); a[4 + r] = f2bs(hi[r]); }
    } else {
      a = *reinterpret_cast<const short8*>(Ab + abase + kt * 32);
    }
    short8 b0 = *reinterpret_cast<const short8*>(W0 + kt * 32);
    short8 b1 = *reinterpret_cast<const short8*>(W1 + kt * 32);
    short8 b2 = *reinterpret_cast<const short8*>(W2 + kt * 32);
    short8 b3 = *reinterpret_cast<const short8*>(W3 + kt * 32);
    acc0 = mfma_bf16(a, b0, acc0);
    acc1 = mfma_bf16(a, b1, acc1);
    acc2 = mfma_bf16(a, b2, acc2);
    acc3 = mfma_bf16(a, b3, acc3);
  }

  floatx4 accs[4] = {acc0, acc1, acc2, acc3};
  #pragma unroll
  for (int nt = 0; nt < 4; ++nt) {
    const int n = nbase + nt * 16 + c;
    const float bv = bias[n];
    #pragma unroll
    for (int r = 0; r < 4; ++r) {
      const int mrow = mtile * 16 + q * 4 + r;
      out[(long)mrow * 2048 + n] = __float2bfloat16(accs[nt][r] + bv);
    }
  }
}

// ---------------------------------------------------------------------------
// Persistent recurrence: 64 blocks x 64 thr (1 wave/block, barrier-free).
// Wave owns 8 h-cols: A-tile0 rows {i,f}, A-tile1 rows {g,o};
// D[m=q*4+r][n=b]: f/o rows in quads 2,3 paired via shfl_xor(.,32).
// Release: h sc0sc1 store -> s_waitcnt vmcnt(0) -> lane0 flag store.
// Acquire: each lane polls one producer flag; __all breaks; bulk h load.
// ---------------------------------------------------------------------------
__global__ __launch_bounds__(64, 1)
void lstm_rec(const bf16* __restrict__ wx, const bf16* __restrict__ U,
              const float* __restrict__ ub, bf16* __restrict__ hseq,
              float* __restrict__ hout, float* __restrict__ hh,
              float* __restrict__ cc, unsigned int* __restrict__ flags)
{
  const int lane  = threadIdx.x;      // 0..63
  const int q     = lane >> 4;
  const int b     = lane & 15;
  const int jbase = blockIdx.x * 8;

  // Preload recurrent weights as A-frags (2 M-tiles x 16 k-frags = 128 VGPR).
  short8 a0[16], a1[16];
  {
    const int row0 = (b < 8) ? (jbase + b) : (512 + jbase + b - 8);           // i | f
    const int row1 = (b < 8) ? (1024 + jbase + b) : (1536 + jbase + b - 8);   // g | o
    const bf16* U0 = U + (long)row0 * 512 + q * 8;
    const bf16* U1 = U + (long)row1 * 512 + q * 8;
    #pragma unroll
    for (int kt = 0; kt < 16; ++kt) {
      a0[kt] = *reinterpret_cast<const short8*>(U0 + kt * 32);
      a1[kt] = *reinterpret_cast<const short8*>(U1 + kt * 32);
    }
  }

  const int jj = jbase + (q & 1) * 4;   // epilogue j-range (meaningful for q<2)
  float ubi[4], ubf[4], ubg[4], ubo[4];
  #pragma unroll
  for (int r = 0; r < 4; ++r) {
    ubi[r] = ub[        jj + r];
    ubf[r] = ub[ 512 + jj + r];
    ubg[r] = ub[1024 + jj + r];
    ubo[r] = ub[1536 + jj + r];
  }

  float cst[4] = {0.f, 0.f, 0.f, 0.f};

  for (int t = 0; t < T_STEPS; ++t) {
    // Prefetch this step's input projection (plain cached loads; producer was
    // a previous dispatch — kernel-boundary release/acquire covers coherence).
    const bf16* wxp = wx + (long)t * 16384 + (b & 7) * 2048 + jj;
    short4v vi = *reinterpret_cast<const short4v*>(wxp);
    short4v vf = *reinterpret_cast<const short4v*>(wxp + 512);
    short4v vg = *reinterpret_cast<const short4v*>(wxp + 1024);
    short4v vo = *reinterpret_cast<const short4v*>(wxp + 1536);

    floatx4 acc0 = {0.f, 0.f, 0.f, 0.f};
    floatx4 acc1 = {0.f, 0.f, 0.f, 0.f};

    if (t > 0) {
      // Wave-wide acquire: lane i polls producer-block i's flag for step t-1.
      const unsigned int* fp = flags + (unsigned)(t - 1) * 64 + lane;
      int guard = 0;
      for (;;) {
        unsigned int v = __hip_atomic_load(fp, __ATOMIC_RELAXED,
                                           __HIP_MEMORY_SCOPE_AGENT);
        if (__all(v != 0u)) break;
        if (++guard > (1 << 24)) break;   // bail instead of hanging
      }

      // One bulk coherent load of h(t-1), then MFMA.
      const bf16* hp = hseq + (long)(t - 1) * 8192 + b * 512 + q * 8;
      u64 hlo[16], hhi[16];
      #pragma unroll
      for (int kt = 0; kt < 16; ++kt) {
        hlo[kt] = cload(hp + kt * 32);
        hhi[kt] = cload(hp + kt * 32 + 4);
      }
      #pragma unroll
      for (int kt = 0; kt < 16; ++kt) {
        union { u64 u[2]; short8 v; } pk;
        pk.u[0] = hlo[kt]; pk.u[1] = hhi[kt];
        acc0 = mfma_bf16(a0[kt], pk.v, acc0);
        acc1 = mfma_bf16(a1[kt], pk.v, acc1);
      }
    }

    float wxi[4], wxf[4], wxg[4], wxo[4];
    #pragma unroll
    for (int r = 0; r < 4; ++r) {
      wxi[r] = bs2f(vi[r]); wxf[r] = bs2f(vf[r]);
      wxg[r] = bs2f(vg[r]); wxo[r] = bs2f(vo[r]);
    }

    // Pair i<->f and g<->o across lane^32 (all lanes execute the shfl).
    float fsh[4], osh[4];
    #pragma unroll
    for (int r = 0; r < 4; ++r) {
      fsh[r] = __shfl_xor(acc0[r], 32, 64);
      osh[r] = __shfl_xor(acc1[r], 32, 64);
    }

    floatx4 hf4, cf4;
    if (q < 2) {
      short4v hp4;
      #pragma unroll
      for (int r = 0; r < 4; ++r) {
        const float pi = acc0[r] + wxi[r] + ubi[r];
        const float pf = fsh[r]  + wxf[r] + ubf[r];
        const float pg = acc1[r] + wxg[r] + ubg[r];
        const float po = osh[r]  + wxo[r] + ubo[r];
        const float it = sigm(pi);
        const float ft = sigm(pf);
        const float gt = tanhf_(pg);
        const float ot = sigm(po);
        const float cv = ft * cst[r] + it * gt;
        cst[r] = cv;
        const float hv = ot * fmaxf(cv, 0.f);   // custom nonlinearity: relu(c)
        hf4[r] = hv;
        cf4[r] = cv;
        hp4[r] = f2bs(hv);
      }
      // h -> coherent point (sc0 sc1), 8B packed.
      union { short4v v; u64 u; } pk; pk.v = hp4;
      __hip_atomic_store(
          reinterpret_cast<u64*>(hseq + (long)t * 8192 + b * 512 + jj),
          pk.u, __ATOMIC_RELAXED, __HIP_MEMORY_SCOPE_AGENT);
    }

    // Release: drain the h store (wave-uniform), then publish this block's flag.
    asm volatile("s_waitcnt vmcnt(0)" ::: "memory");
    if (lane == 0) {
      __hip_atomic_store(flags + (unsigned)t * 64 + blockIdx.x, 1u,
                         __ATOMIC_RELAXED, __HIP_MEMORY_SCOPE_AGENT);
    }

    // Fire-and-forget outputs AFTER the flag (never on the critical chain).
    if (q < 2 && b < 8) {
      if (hout != nullptr) {                   // layer-1: h2 -> d_out fp32
        *reinterpret_cast<floatx4*>(hout + (long)b * 1048576 + (long)t * 512 + jj) = hf4;
      }
      if (t == T_STEPS - 1) {                  // final h/c states fp32
        *reinterpret_cast<floatx4*>(hh + b * 512 + jj) = hf4;
        *reinterpret_cast<floatx4*>(cc + b * 512 + jj) = cf4;
      }
    }
  }
}

extern "C" void kernel_launch(void* const* d_in, const int* in_sizes, int n_in,
                              void* d_out, int out_size, void* d_ws, size_t ws_size,
                              hipStream_t stream) {
  (void)in_sizes; (void)n_in; (void)out_size; (void)ws_size;
  const float* x   = (const float*)d_in[0];
  const float* w0w = (const float*)d_in[1];
  const float* w0b = (const float*)d_in[2];
  const float* u0w = (const float*)d_in[3];
  const float* u0b = (const float*)d_in[4];
  const float* w1w = (const float*)d_in[5];
  const float* w1b = (const float*)d_in[6];
  const float* u1w = (const float*)d_in[7];
  const float* u1b = (const float*)d_in[8];
  float* out = (float*)d_out;

  char* ws = (char*)d_ws;
  unsigned int* flags0 = (unsigned int*)ws;
  unsigned int* flags1 = (unsigned int*)(ws + (size_t)524288);
  bf16* Wb0 = (bf16*)(ws + (size_t)1048576);
  bf16* Ub0 = (bf16*)(ws + (size_t)2097152);
  bf16* Wb1 = (bf16*)(ws + (size_t)4194304);
  bf16* Ub1 = (bf16*)(ws + (size_t)6291456);
  bf16* wx  = (bf16*)(ws + (size_t)8388608);
  bf16* h1s = (bf16*)(ws + (size_t)75497472);
  bf16* h2s = (bf16*)(ws + (size_t)109051904);

  hipMemsetAsync(ws, 0, 1048576, stream);   // zero both flag arrays

  // Weight conversions fp32 -> bf16.
  cvt_f32_bf16<<<512,  256, 0, stream>>>(w0w, Wb0, 524288);
  cvt_f32_bf16<<<1024, 256, 0, stream>>>(u0w, Ub0, 1048576);
  cvt_f32_bf16<<<1024, 256, 0, stream>>>(w1w, Wb1, 1048576);
  cvt_f32_bf16<<<1024, 256, 0, stream>>>(u1w, Ub1, 1048576);

  dim3 gg(1024, 8, 1);
  // Layer 0 input projection: A = x[b][t][d] fp32.
  gemm_proj<<<gg, 256, 0, stream>>>(x, nullptr, Wb0, w0b, wx, 256, 2048 * 256, 256);
  // Layer 0 recurrence.
  lstm_rec<<<NB_REC, 64, 0, stream>>>(wx, Ub0, u0b, h1s, nullptr,
                                      out + HH_OFF, out + CC_OFF, flags0);
  // Layer 1 input projection: A = h1s[t][16][512] bf16.
  gemm_proj<<<gg, 256, 0, stream>>>(nullptr, h1s, Wb1, w1b, wx, 512, 512, 8192);
  // Layer 1 recurrence (writes h2 fp32 to d_out).
  lstm_rec<<<NB_REC, 64, 0, stream>>>(wx, Ub1, u1b, h2s, out,
                                      out + HH_OFF + 4096, out + CC_OFF + 4096, flags1);
}

// Round 6
// 11498.287 us; speedup vs baseline: 2.6984x; 1.8803x over previous
//
#include <hip/hip_runtime.h>
#include <hip/hip_bf16.h>
#include <stdint.h>

// LSTM_48601849922171 — 2-layer LSTM (B=8, T=2048, D_IN=256, H=512), fp32 I/O,
// bf16 MFMA compute.
//
// Round 6: FUSED recurrence. One persistent kernel, 128 blocks x 64 thr:
// blocks 0..63 = layer 0 (K=512: U0·h1), blocks 64..127 = layer 1
// (K=1024: [W1|U1]·[h1(t); h2(t-1)] — the L1 input projection is folded in,
// so the wx1 GEMM is gone and both layers pipeline concurrently; serial
// length ~2049 steps instead of 4096).
//
// Sync = payload-as-flag: a block's per-step output is 128 B (8 cols x 8
// batches bf16) stored as 16 contiguous u64 (sc0sc1 -> coherent IC) into a
// 0xFF-pre-filled region (h >= 0 so data never equals the sentinel).
// Consumer lane L polls producer-block L's 128 B region with UNCONDITIONAL
// back-to-back reloads (one IC latency per sweep), then scatters to LDS and
// reads MFMA B-frags. No fences, no barriers, no drain, no separate flags.
//
// Workspace (~103 MB):
//   0:        payl0 [2048][64][16] u64 = 16 MB  (memset 0xFF)
//   16M:      payl1 16 MB                        (memset 0xFF)
//   32M:      Wb0 1MB | 33M: Ub0 2MB | 35M: Wb1 2MB | 37M: Ub1 2MB
//   39M:      wx0 [2048][8][2048] bf16 = 64 MB (layer-0 input projection)

typedef __hip_bfloat16 bf16;
typedef float  floatx4 __attribute__((ext_vector_type(4)));
typedef short  short8  __attribute__((ext_vector_type(8)));
typedef short  short4v __attribute__((ext_vector_type(4)));
typedef unsigned long long u64;

#define T_STEPS  2048
#define SENT64   0xFFFFFFFFFFFFFFFFull
#define HH_OFF   8388608   // 8*2048*512
#define CC_OFF   8396800   // HH_OFF + 2*8*512
#define STR0     1056      // LDS row stride bytes, layer 0 ([8][512+pad])
#define STR1     2080      // LDS row stride bytes, layer 1 ([8][1024+pad])

static __device__ __forceinline__ float bs2f(short s) {
  union { unsigned int u; float f; } c;
  c.u = ((unsigned int)(unsigned short)s) << 16;
  return c.f;
}
static __device__ __forceinline__ short f2bs(float x) {
  union { bf16 h; short s; } u;
  u.h = __float2bfloat16(x);
  return u.s;
}
static __device__ __forceinline__ float sigm(float x) {
  x = fminf(fmaxf(x, -30.f), 30.f);
  return 1.f / (1.f + __expf(-x));
}
static __device__ __forceinline__ float tanhf_(float x) {
  x = fminf(fmaxf(x, -15.f), 15.f);
  float e = __expf(2.f * x);
  return (e - 1.f) / (e + 1.f);
}
static __device__ __forceinline__ floatx4 mfma_bf16(short8 a, short8 b, floatx4 c) {
  return __builtin_amdgcn_mfma_f32_16x16x32_bf16(a, b, c, 0, 0, 0);
}
static __device__ __forceinline__ u64 cload(const u64* p) {
  return __hip_atomic_load(p, __ATOMIC_RELAXED, __HIP_MEMORY_SCOPE_AGENT);
}
static __device__ __forceinline__ void cstore(u64* p, u64 v) {
  __hip_atomic_store(p, v, __ATOMIC_RELAXED, __HIP_MEMORY_SCOPE_AGENT);
}

// fp32 -> bf16 elementwise (n multiple of 4)
__global__ __launch_bounds__(256)
void cvt_f32_bf16(const float* __restrict__ src, bf16* __restrict__ dst, int n) {
  int i = (blockIdx.x * 256 + threadIdx.x) * 4;
  if (i < n) {
    floatx4 v = *reinterpret_cast<const floatx4*>(src + i);
    short4v o;
    #pragma unroll
    for (int r = 0; r < 4; ++r) o[r] = f2bs(v[r]);
    *reinterpret_cast<short4v*>(dst + i) = o;
  }
}

// ---------------------------------------------------------------------------
// Layer-0 input projection: out[m][n] = sum_k A[m][k]*W[n][k] + bias[n],
// m = t*8+b. Block 256 thr; wave tile M=16 x N=64; grid (1024, 8).
// ---------------------------------------------------------------------------
__global__ __launch_bounds__(256)
void gemm_proj(const float* __restrict__ Af, const bf16* __restrict__ W,
               const float* __restrict__ bias, bf16* __restrict__ out,
               int K, int strideB, int strideT)
{
  const int lane  = threadIdx.x & 63;
  const int wave  = threadIdx.x >> 6;
  const int q     = lane >> 4;
  const int c     = lane & 15;
  const int mtile = blockIdx.x;
  const int nbase = blockIdx.y * 256 + wave * 64;
  const int m     = mtile * 16 + c;

  const long abase = (long)(m & 7) * strideB + (long)(m >> 3) * strideT + q * 8;
  const bf16* W0 = W + (long)(nbase +  0 + c) * K + q * 8;
  const bf16* W1 = W + (long)(nbase + 16 + c) * K + q * 8;
  const bf16* W2 = W + (long)(nbase + 32 + c) * K + q * 8;
  const bf16* W3 = W + (long)(nbase + 48 + c) * K + q * 8;

  floatx4 acc0 = {0.f, 0.f, 0.f, 0.f};
  floatx4 acc1 = acc0, acc2 = acc0, acc3 = acc0;
  const int nk = K >> 5;
  for (int kt = 0; kt < nk; ++kt) {
    short8 a;
    floatx4 lo = *reinterpret_cast<const floatx4*>(Af + abase + kt * 32);
    floatx4 hi = *reinterpret_cast<const floatx4*>(Af + abase + kt * 32 + 4);
    #pragma unroll
    for (int r = 0; r < 4; ++r) { a[r] = f2bs(lo[r]); a[4 + r] = f2bs(hi[r]); }
    short8 b0 = *reinterpret_cast<const short8*>(W0 + kt * 32);
    short8 b1 = *reinterpret_cast<const short8*>(W1 + kt * 32);
    short8 b2 = *reinterpret_cast<const short8*>(W2 + kt * 32);
    short8 b3 = *reinterpret_cast<const short8*>(W3 + kt * 32);
    acc0 = mfma_bf16(a, b0, acc0);
    acc1 = mfma_bf16(a, b1, acc1);
    acc2 = mfma_bf16(a, b2, acc2);
    acc3 = mfma_bf16(a, b3, acc3);
  }

  floatx4 accs[4] = {acc0, acc1, acc2, acc3};
  #pragma unroll
  for (int nt = 0; nt < 4; ++nt) {
    const int n = nbase + nt * 16 + c;
    const float bv = bias[n];
    #pragma unroll
    for (int r = 0; r < 4; ++r) {
      const int mrow = mtile * 16 + q * 4 + r;
      out[(long)mrow * 2048 + n] = __float2bfloat16(accs[nt][r] + bv);
    }
  }
}

// ---------------------------------------------------------------------------
// Fused 2-layer persistent recurrence. 128 blocks x 64 thr (1 wave/block).
// layer = blockIdx.x>>6, blk = blockIdx.x&63; block owns h-cols 8*blk..+8.
// A-tile0 rows {i,f}, tile1 rows {g,o}; D[m=q*4+r][n=b], f/o via shfl_xor 32.
// ---------------------------------------------------------------------------
__global__ __launch_bounds__(64, 1)
void lstm_fused(const bf16* __restrict__ wx, const bf16* __restrict__ Ub0,
                const bf16* __restrict__ Wb1, const bf16* __restrict__ Ub1,
                const float* __restrict__ ub0, const float* __restrict__ w1b,
                const float* __restrict__ u1b, float* __restrict__ out,
                u64* __restrict__ payl0, u64* __restrict__ payl1)
{
  __shared__ char lds[8 * STR1];     // L0 uses 8*STR0 of it
  const int lane  = threadIdx.x;     // 0..63
  const int q     = lane >> 4;
  const int b     = lane & 15;
  const int layer = blockIdx.x >> 6;
  const int blk   = blockIdx.x & 63;
  const int jbase = blk * 8;
  const int jj    = jbase + (q & 1) * 4;

  const int row0 = (b < 8) ? (jbase + b) : (512 + jbase + b - 8);           // i | f
  const int row1 = (b < 8) ? (1024 + jbase + b) : (1536 + jbase + b - 8);   // g | o

  float* hh = out + ((layer == 0) ? HH_OFF : HH_OFF + 4096);
  float* cc = out + ((layer == 0) ? CC_OFF : CC_OFF + 4096);

  if (layer == 0) {
    // ---- Layer 0: K=512 (U0 * h1(t-1)) + precomputed wx ----
    short8 a0[16], a1[16];
    {
      const bf16* U0p = Ub0 + (long)row0 * 512 + q * 8;
      const bf16* U1p = Ub0 + (long)row1 * 512 + q * 8;
      #pragma unroll
      for (int kt = 0; kt < 16; ++kt) {
        a0[kt] = *reinterpret_cast<const short8*>(U0p + kt * 32);
        a1[kt] = *reinterpret_cast<const short8*>(U1p + kt * 32);
      }
    }
    float ubi[4], ubf[4], ubg[4], ubo[4];
    #pragma unroll
    for (int r = 0; r < 4; ++r) {
      ubi[r] = ub0[        jj + r];
      ubf[r] = ub0[ 512 + jj + r];
      ubg[r] = ub0[1024 + jj + r];
      ubo[r] = ub0[1536 + jj + r];
    }
    float cst[4] = {0.f, 0.f, 0.f, 0.f};

    for (int t = 0; t < T_STEPS; ++t) {
      const bf16* wxp = wx + (long)t * 16384 + (b & 7) * 2048 + jj;
      short4v vi = *reinterpret_cast<const short4v*>(wxp);
      short4v vf = *reinterpret_cast<const short4v*>(wxp + 512);
      short4v vg = *reinterpret_cast<const short4v*>(wxp + 1024);
      short4v vo = *reinterpret_cast<const short4v*>(wxp + 1536);

      floatx4 acc0 = {0.f, 0.f, 0.f, 0.f};
      floatx4 acc1 = {0.f, 0.f, 0.f, 0.f};

      if (t > 0) {
        // Poll producer-block `lane`'s 128B payload for step t-1.
        const u64* pp = payl0 + ((long)(t - 1)) * 1024 + lane * 16;
        u64 w[16];
        int guard = 0;
        for (;;) {
          int ok = 1;
          #pragma unroll
          for (int i = 0; i < 16; ++i) {
            w[i] = cload(pp + i);
            ok &= (w[i] != SENT64);
          }
          if (__all(ok)) break;
          if (++guard > (1 << 22)) break;
        }
        // Scatter to LDS: lds[b8][col], col = 8*lane + 4*half (+c).
        #pragma unroll
        for (int i = 0; i < 16; ++i) {
          *reinterpret_cast<u64*>(lds + (i >> 1) * STR0 + lane * 16 + (i & 1) * 8) = w[i];
        }
        #pragma unroll
        for (int kt = 0; kt < 16; ++kt) {
          short8 hb = *reinterpret_cast<const short8*>(
              lds + (b & 7) * STR0 + kt * 64 + q * 16);
          acc0 = mfma_bf16(a0[kt], hb, acc0);
          acc1 = mfma_bf16(a1[kt], hb, acc1);
        }
      }

      float wxi[4], wxf[4], wxg[4], wxo[4];
      #pragma unroll
      for (int r = 0; r < 4; ++r) {
        wxi[r] = bs2f(vi[r]); wxf[r] = bs2f(vf[r]);
        wxg[r] = bs2f(vg[r]); wxo[r] = bs2f(vo[r]);
      }
      float fsh[4], osh[4];
      #pragma unroll
      for (int r = 0; r < 4; ++r) {
        fsh[r] = __shfl_xor(acc0[r], 32, 64);
        osh[r] = __shfl_xor(acc1[r], 32, 64);
      }

      if (q < 2 && b < 8) {
        short4v hp4; floatx4 hf4, cf4;
        #pragma unroll
        for (int r = 0; r < 4; ++r) {
          const float pi = acc0[r] + wxi[r] + ubi[r];
          const float pf = fsh[r]  + wxf[r] + ubf[r];
          const float pg = acc1[r] + wxg[r] + ubg[r];
          const float po = osh[r]  + wxo[r] + ubo[r];
          const float it = sigm(pi), ft = sigm(pf);
          const float gt = tanhf_(pg), ot = sigm(po);
          const float cv = ft * cst[r] + it * gt;
          cst[r] = cv;
          const float hv = ot * fmaxf(cv, 0.f);
          hf4[r] = hv; cf4[r] = cv; hp4[r] = f2bs(hv);
        }
        union { short4v v; u64 u; } pk; pk.v = hp4;
        cstore(payl0 + (long)t * 1024 + blk * 16 + (b * 2 + (q & 1)), pk.u);
        if (t == T_STEPS - 1) {
          *reinterpret_cast<floatx4*>(hh + b * 512 + jj) = hf4;
          *reinterpret_cast<floatx4*>(cc + b * 512 + jj) = cf4;
        }
      } else {
        // keep epilogue VALU minimal on non-owning lanes (still run shfl above)
        #pragma unroll
        for (int r = 0; r < 4; ++r) cst[r] = cst[r];
      }
    }
  } else {
    // ---- Layer 1: K=1024 ([W1|U1] * [h1(t); h2(t-1)]) ----
    short8 a0[32], a1[32];
    {
      const bf16* W0p = Wb1 + (long)row0 * 512 + q * 8;
      const bf16* W1p = Wb1 + (long)row1 * 512 + q * 8;
      const bf16* U0p = Ub1 + (long)row0 * 512 + q * 8;
      const bf16* U1p = Ub1 + (long)row1 * 512 + q * 8;
      #pragma unroll
      for (int kt = 0; kt < 16; ++kt) {
        a0[kt]      = *reinterpret_cast<const short8*>(W0p + kt * 32);
        a1[kt]      = *reinterpret_cast<const short8*>(W1p + kt * 32);
        a0[16 + kt] = *reinterpret_cast<const short8*>(U0p + kt * 32);
        a1[16 + kt] = *reinterpret_cast<const short8*>(U1p + kt * 32);
      }
    }
    float ubi[4], ubf[4], ubg[4], ubo[4];
    #pragma unroll
    for (int r = 0; r < 4; ++r) {
      ubi[r] = w1b[        jj + r] + u1b[        jj + r];
      ubf[r] = w1b[ 512 + jj + r] + u1b[ 512 + jj + r];
      ubg[r] = w1b[1024 + jj + r] + u1b[1024 + jj + r];
      ubo[r] = w1b[1536 + jj + r] + u1b[1536 + jj + r];
    }
    float cst[4] = {0.f, 0.f, 0.f, 0.f};

    for (int t = 0; t < T_STEPS; ++t) {
      floatx4 acc0 = {0.f, 0.f, 0.f, 0.f};
      floatx4 acc1 = {0.f, 0.f, 0.f, 0.f};

      // Merged poll: h1(t) from L0, h2(t-1) from own layer (skip at t=0).
      const u64* p0 = payl0 + (long)t * 1024 + lane * 16;
      u64 w0[16], w1[16];
      int guard = 0;
      if (t > 0) {
        const u64* p1 = payl1 + ((long)(t - 1)) * 1024 + lane * 16;
        for (;;) {
          int ok = 1;
          #pragma unroll
          for (int i = 0; i < 16; ++i) {
            w1[i] = cload(p1 + i);
            ok &= (w1[i] != SENT64);
          }
          #pragma unroll
          for (int i = 0; i < 16; ++i) {
            w0[i] = cload(p0 + i);
            ok &= (w0[i] != SENT64);
          }
          if (__all(ok)) break;
          if (++guard > (1 << 22)) break;
        }
      } else {
        for (;;) {
          int ok = 1;
          #pragma unroll
          for (int i = 0; i < 16; ++i) {
            w0[i] = cload(p0 + i);
            ok &= (w0[i] != SENT64);
          }
          if (__all(ok)) break;
          if (++guard > (1 << 22)) break;
        }
      }
      // Scatter: h1 at cols 0..511, h2 at cols 512..1023.
      #pragma unroll
      for (int i = 0; i < 16; ++i) {
        *reinterpret_cast<u64*>(lds + (i >> 1) * STR1 + lane * 16 + (i & 1) * 8) = w0[i];
      }
      if (t > 0) {
        #pragma unroll
        for (int i = 0; i < 16; ++i) {
          *reinterpret_cast<u64*>(lds + (i >> 1) * STR1 + 1024 + lane * 16 + (i & 1) * 8) = w1[i];
        }
      }
      #pragma unroll
      for (int kt = 0; kt < 16; ++kt) {
        short8 hb = *reinterpret_cast<const short8*>(
            lds + (b & 7) * STR1 + kt * 64 + q * 16);
        acc0 = mfma_bf16(a0[kt], hb, acc0);
        acc1 = mfma_bf16(a1[kt], hb, acc1);
      }
      if (t > 0) {
        #pragma unroll
        for (int kt = 16; kt < 32; ++kt) {
          short8 hb = *reinterpret_cast<const short8*>(
              lds + (b & 7) * STR1 + kt * 64 + q * 16);
          acc0 = mfma_bf16(a0[kt], hb, acc0);
          acc1 = mfma_bf16(a1[kt], hb, acc1);
        }
      }

      float fsh[4], osh[4];
      #pragma unroll
      for (int r = 0; r < 4; ++r) {
        fsh[r] = __shfl_xor(acc0[r], 32, 64);
        osh[r] = __shfl_xor(acc1[r], 32, 64);
      }

      if (q < 2 && b < 8) {
        short4v hp4; floatx4 hf4, cf4;
        #pragma unroll
        for (int r = 0; r < 4; ++r) {
          const float pi = acc0[r] + ubi[r];
          const float pf = fsh[r]  + ubf[r];
          const float pg = acc1[r] + ubg[r];
          const float po = osh[r]  + ubo[r];
          const float it = sigm(pi), ft = sigm(pf);
          const float gt = tanhf_(pg), ot = sigm(po);
          const float cv = ft * cst[r] + it * gt;
          cst[r] = cv;
          const float hv = ot * fmaxf(cv, 0.f);
          hf4[r] = hv; cf4[r] = cv; hp4[r] = f2bs(hv);
        }
        union { short4v v; u64 u; } pk; pk.v = hp4;
        cstore(payl1 + (long)t * 1024 + blk * 16 + (b * 2 + (q & 1)), pk.u);
        // h2 -> d_out fp32 (off critical chain).
        *reinterpret_cast<floatx4*>(out + (long)b * 1048576 + (long)t * 512 + jj) = hf4;
        if (t == T_STEPS - 1) {
          *reinterpret_cast<floatx4*>(hh + b * 512 + jj) = hf4;
          *reinterpret_cast<floatx4*>(cc + b * 512 + jj) = cf4;
        }
      }
    }
  }
}

extern "C" void kernel_launch(void* const* d_in, const int* in_sizes, int n_in,
                              void* d_out, int out_size, void* d_ws, size_t ws_size,
                              hipStream_t stream) {
  (void)in_sizes; (void)n_in; (void)out_size; (void)ws_size;
  const float* x   = (const float*)d_in[0];
  const float* w0w = (const float*)d_in[1];
  const float* w0b = (const float*)d_in[2];
  const float* u0w = (const float*)d_in[3];
  const float* u0b = (const float*)d_in[4];
  const float* w1w = (const float*)d_in[5];
  const float* w1b = (const float*)d_in[6];
  const float* u1w = (const float*)d_in[7];
  const float* u1b = (const float*)d_in[8];
  float* out = (float*)d_out;

  char* ws = (char*)d_ws;
  u64*  payl0 = (u64*)ws;
  u64*  payl1 = (u64*)(ws + (size_t)16777216);
  bf16* Wb0 = (bf16*)(ws + (size_t)33554432);
  bf16* Ub0 = (bf16*)(ws + (size_t)34603008);
  bf16* Wb1 = (bf16*)(ws + (size_t)36700160);
  bf16* Ub1 = (bf16*)(ws + (size_t)38797312);
  bf16* wx  = (bf16*)(ws + (size_t)40894464);

  // Sentinel-fill both payload arrays (32 MB of 0xFF).
  hipMemsetAsync(ws, 0xFF, (size_t)33554432, stream);

  // Weight conversions fp32 -> bf16.
  cvt_f32_bf16<<<512,  256, 0, stream>>>(w0w, Wb0, 524288);
  cvt_f32_bf16<<<1024, 256, 0, stream>>>(u0w, Ub0, 1048576);
  cvt_f32_bf16<<<1024, 256, 0, stream>>>(w1w, Wb1, 1048576);
  cvt_f32_bf16<<<1024, 256, 0, stream>>>(u1w, Ub1, 1048576);

  // Layer-0 input projection.
  dim3 gg(1024, 8, 1);
  gemm_proj<<<gg, 256, 0, stream>>>(x, Wb0, w0b, wx, 256, 2048 * 256, 256);

  // Fused 2-layer recurrence.
  lstm_fused<<<128, 64, 0, stream>>>(wx, Ub0, Wb1, Ub1, u0b, w1b, u1b,
                                     out, payl0, payl1);
}

// Round 7
// 11446.768 us; speedup vs baseline: 2.7105x; 1.0045x over previous
//
#include <hip/hip_runtime.h>
#include <hip/hip_bf16.h>
#include <stdint.h>

// LSTM_48601849922171 — 2-layer LSTM (B=8, T=2048, D_IN=256, H=512), fp32 I/O,
// bf16 MFMA compute.
//
// Round 7: R6 fused recurrence + HEATER waves (DVFS experiment). Per-step
// latency has been pinned at ~5.4us across 5 different sync structures while
// all pipes idle => hypothesis: GFXCLK parked at idle floor (~450MHz) because
// chip utilization is 0.7%. Heater waves (pure independent v_fmac_f32 spin,
// polling a done-counter) drive utilization up so the governor boosts clocks.
//   - 512 blocks x 256 thr: blocks 0..127 wave 0 = recurrence (identical to
//     R6, s_setprio 3); all other waves = heater.
//   - 2048 waves total, <=256 VGPR => all co-resident, no deadlock; heaters
//     exit when all 128 rec waves bump `done`.
//
// Workspace (~111 MB):
//   0:        payl0 [2048][64][16] u64 = 16 MB  (memset 0xFF)
//   16M:      payl1 16 MB                        (memset 0xFF)
//   32M:      Wb0 1MB | 33M: Ub0 2MB | 35M: Wb1 2MB | 37M: Ub1 2MB
//   39M:      wx0 [2048][8][2048] bf16 = 64 MB
//   115343360: done u32 (memset 0)

typedef __hip_bfloat16 bf16;
typedef float  floatx4 __attribute__((ext_vector_type(4)));
typedef short  short8  __attribute__((ext_vector_type(8)));
typedef short  short4v __attribute__((ext_vector_type(4)));
typedef unsigned long long u64;

#define T_STEPS  2048
#define SENT64   0xFFFFFFFFFFFFFFFFull
#define HH_OFF   8388608   // 8*2048*512
#define CC_OFF   8396800   // HH_OFF + 2*8*512
#define STR0     1056      // LDS row stride bytes, layer 0 ([8][512+pad])
#define STR1     2080      // LDS row stride bytes, layer 1 ([8][1024+pad])
#define N_REC_BLK 128
#define N_BLK     512

static __device__ __forceinline__ float bs2f(short s) {
  union { unsigned int u; float f; } c;
  c.u = ((unsigned int)(unsigned short)s) << 16;
  return c.f;
}
static __device__ __forceinline__ short f2bs(float x) {
  union { bf16 h; short s; } u;
  u.h = __float2bfloat16(x);
  return u.s;
}
static __device__ __forceinline__ float sigm(float x) {
  x = fminf(fmaxf(x, -30.f), 30.f);
  return 1.f / (1.f + __expf(-x));
}
static __device__ __forceinline__ float tanhf_(float x) {
  x = fminf(fmaxf(x, -15.f), 15.f);
  float e = __expf(2.f * x);
  return (e - 1.f) / (e + 1.f);
}
static __device__ __forceinline__ floatx4 mfma_bf16(short8 a, short8 b, floatx4 c) {
  return __builtin_amdgcn_mfma_f32_16x16x32_bf16(a, b, c, 0, 0, 0);
}
static __device__ __forceinline__ u64 cload(const u64* p) {
  return __hip_atomic_load(p, __ATOMIC_RELAXED, __HIP_MEMORY_SCOPE_AGENT);
}
static __device__ __forceinline__ void cstore(u64* p, u64 v) {
  __hip_atomic_store(p, v, __ATOMIC_RELAXED, __HIP_MEMORY_SCOPE_AGENT);
}

// fp32 -> bf16 elementwise (n multiple of 4)
__global__ __launch_bounds__(256)
void cvt_f32_bf16(const float* __restrict__ src, bf16* __restrict__ dst, int n) {
  int i = (blockIdx.x * 256 + threadIdx.x) * 4;
  if (i < n) {
    floatx4 v = *reinterpret_cast<const floatx4*>(src + i);
    short4v o;
    #pragma unroll
    for (int r = 0; r < 4; ++r) o[r] = f2bs(v[r]);
    *reinterpret_cast<short4v*>(dst + i) = o;
  }
}

// ---------------------------------------------------------------------------
// Layer-0 input projection: out[m][n] = sum_k A[m][k]*W[n][k] + bias[n],
// m = t*8+b. Block 256 thr; wave tile M=16 x N=64; grid (1024, 8).
// ---------------------------------------------------------------------------
__global__ __launch_bounds__(256)
void gemm_proj(const float* __restrict__ Af, const bf16* __restrict__ W,
               const float* __restrict__ bias, bf16* __restrict__ out,
               int K, int strideB, int strideT)
{
  const int lane  = threadIdx.x & 63;
  const int wave  = threadIdx.x >> 6;
  const int q     = lane >> 4;
  const int c     = lane & 15;
  const int mtile = blockIdx.x;
  const int nbase = blockIdx.y * 256 + wave * 64;
  const int m     = mtile * 16 + c;

  const long abase = (long)(m & 7) * strideB + (long)(m >> 3) * strideT + q * 8;
  const bf16* W0 = W + (long)(nbase +  0 + c) * K + q * 8;
  const bf16* W1 = W + (long)(nbase + 16 + c) * K + q * 8;
  const bf16* W2 = W + (long)(nbase + 32 + c) * K + q * 8;
  const bf16* W3 = W + (long)(nbase + 48 + c) * K + q * 8;

  floatx4 acc0 = {0.f, 0.f, 0.f, 0.f};
  floatx4 acc1 = acc0, acc2 = acc0, acc3 = acc0;
  const int nk = K >> 5;
  for (int kt = 0; kt < nk; ++kt) {
    short8 a;
    floatx4 lo = *reinterpret_cast<const floatx4*>(Af + abase + kt * 32);
    floatx4 hi = *reinterpret_cast<const floatx4*>(Af + abase + kt * 32 + 4);
    #pragma unroll
    for (int r = 0; r < 4; ++r) { a[r] = f2bs(lo[r]); a[4 + r] = f2bs(hi[r]); }
    short8 b0 = *reinterpret_cast<const short8*>(W0 + kt * 32);
    short8 b1 = *reinterpret_cast<const short8*>(W1 + kt * 32);
    short8 b2 = *reinterpret_cast<const short8*>(W2 + kt * 32);
    short8 b3 = *reinterpret_cast<const short8*>(W3 + kt * 32);
    acc0 = mfma_bf16(a, b0, acc0);
    acc1 = mfma_bf16(a, b1, acc1);
    acc2 = mfma_bf16(a, b2, acc2);
    acc3 = mfma_bf16(a, b3, acc3);
  }

  floatx4 accs[4] = {acc0, acc1, acc2, acc3};
  #pragma unroll
  for (int nt = 0; nt < 4; ++nt) {
    const int n = nbase + nt * 16 + c;
    const float bv = bias[n];
    #pragma unroll
    for (int r = 0; r < 4; ++r) {
      const int mrow = mtile * 16 + q * 4 + r;
      out[(long)mrow * 2048 + n] = __float2bfloat16(accs[nt][r] + bv);
    }
  }
}

// ---------------------------------------------------------------------------
// Fused 2-layer persistent recurrence + heater. 512 blocks x 256 thr.
// Rec: blocks 0..127, wave 0 only. layer = blockIdx.x>>6, blk = blockIdx.x&63.
// All other waves: FMA heater spinning until done==128 (keeps GFXCLK up).
// ---------------------------------------------------------------------------
__global__ __launch_bounds__(256)
void lstm_fused(const bf16* __restrict__ wx, const bf16* __restrict__ Ub0,
                const bf16* __restrict__ Wb1, const bf16* __restrict__ Ub1,
                const float* __restrict__ ub0, const float* __restrict__ w1b,
                const float* __restrict__ u1b, float* __restrict__ out,
                u64* __restrict__ payl0, u64* __restrict__ payl1,
                unsigned int* __restrict__ done)
{
  __shared__ char lds[8 * STR1];     // L0 uses 8*STR0 of it
  const int wv = threadIdx.x >> 6;

  if (blockIdx.x >= N_REC_BLK || wv != 0) {
    // ---------------- heater ----------------
    float a0 = (float)threadIdx.x, a1 = a0 + 1.f, a2 = a0 + 2.f, a3 = a0 + 3.f;
    float a4 = a0 + 4.f, a5 = a0 + 5.f, a6 = a0 + 6.f, a7 = a0 + 7.f;
    const float xm = 1.0000001f, ya = 1e-7f;
    int g = 0;
    for (;;) {
      #pragma unroll
      for (int it = 0; it < 64; ++it) {
        asm volatile("v_fmac_f32 %0, %1, %2" : "+v"(a0) : "v"(xm), "v"(ya));
        asm volatile("v_fmac_f32 %0, %1, %2" : "+v"(a1) : "v"(xm), "v"(ya));
        asm volatile("v_fmac_f32 %0, %1, %2" : "+v"(a2) : "v"(xm), "v"(ya));
        asm volatile("v_fmac_f32 %0, %1, %2" : "+v"(a3) : "v"(xm), "v"(ya));
        asm volatile("v_fmac_f32 %0, %1, %2" : "+v"(a4) : "v"(xm), "v"(ya));
        asm volatile("v_fmac_f32 %0, %1, %2" : "+v"(a5) : "v"(xm), "v"(ya));
        asm volatile("v_fmac_f32 %0, %1, %2" : "+v"(a6) : "v"(xm), "v"(ya));
        asm volatile("v_fmac_f32 %0, %1, %2" : "+v"(a7) : "v"(xm), "v"(ya));
      }
      if (__hip_atomic_load(done, __ATOMIC_RELAXED,
                            __HIP_MEMORY_SCOPE_AGENT) >= (unsigned)N_REC_BLK) break;
      if (++g > (1 << 22)) break;
    }
    return;
  }

  // ---------------- recurrence (wave 0 of blocks 0..127) ----------------
  asm volatile("s_setprio 3" ::: "memory");
  const int lane  = threadIdx.x;     // 0..63
  const int q     = lane >> 4;
  const int b     = lane & 15;
  const int layer = blockIdx.x >> 6;
  const int blk   = blockIdx.x & 63;
  const int jbase = blk * 8;
  const int jj    = jbase + (q & 1) * 4;

  const int row0 = (b < 8) ? (jbase + b) : (512 + jbase + b - 8);           // i | f
  const int row1 = (b < 8) ? (1024 + jbase + b) : (1536 + jbase + b - 8);   // g | o

  float* hh = out + ((layer == 0) ? HH_OFF : HH_OFF + 4096);
  float* cc = out + ((layer == 0) ? CC_OFF : CC_OFF + 4096);

  if (layer == 0) {
    // ---- Layer 0: K=512 (U0 * h1(t-1)) + precomputed wx ----
    short8 a0[16], a1[16];
    {
      const bf16* U0p = Ub0 + (long)row0 * 512 + q * 8;
      const bf16* U1p = Ub0 + (long)row1 * 512 + q * 8;
      #pragma unroll
      for (int kt = 0; kt < 16; ++kt) {
        a0[kt] = *reinterpret_cast<const short8*>(U0p + kt * 32);
        a1[kt] = *reinterpret_cast<const short8*>(U1p + kt * 32);
      }
    }
    float ubi[4], ubf[4], ubg[4], ubo[4];
    #pragma unroll
    for (int r = 0; r < 4; ++r) {
      ubi[r] = ub0[        jj + r];
      ubf[r] = ub0[ 512 + jj + r];
      ubg[r] = ub0[1024 + jj + r];
      ubo[r] = ub0[1536 + jj + r];
    }
    float cst[4] = {0.f, 0.f, 0.f, 0.f};

    for (int t = 0; t < T_STEPS; ++t) {
      const bf16* wxp = wx + (long)t * 16384 + (b & 7) * 2048 + jj;
      short4v vi = *reinterpret_cast<const short4v*>(wxp);
      short4v vf = *reinterpret_cast<const short4v*>(wxp + 512);
      short4v vg = *reinterpret_cast<const short4v*>(wxp + 1024);
      short4v vo = *reinterpret_cast<const short4v*>(wxp + 1536);

      floatx4 acc0 = {0.f, 0.f, 0.f, 0.f};
      floatx4 acc1 = {0.f, 0.f, 0.f, 0.f};

      if (t > 0) {
        const u64* pp = payl0 + ((long)(t - 1)) * 1024 + lane * 16;
        u64 w[16];
        int guard = 0;
        for (;;) {
          int ok = 1;
          #pragma unroll
          for (int i = 0; i < 16; ++i) {
            w[i] = cload(pp + i);
            ok &= (w[i] != SENT64);
          }
          if (__all(ok)) break;
          if (++guard > (1 << 22)) break;
        }
        #pragma unroll
        for (int i = 0; i < 16; ++i) {
          *reinterpret_cast<u64*>(lds + (i >> 1) * STR0 + lane * 16 + (i & 1) * 8) = w[i];
        }
        #pragma unroll
        for (int kt = 0; kt < 16; ++kt) {
          short8 hb = *reinterpret_cast<const short8*>(
              lds + (b & 7) * STR0 + kt * 64 + q * 16);
          acc0 = mfma_bf16(a0[kt], hb, acc0);
          acc1 = mfma_bf16(a1[kt], hb, acc1);
        }
      }

      float wxi[4], wxf[4], wxg[4], wxo[4];
      #pragma unroll
      for (int r = 0; r < 4; ++r) {
        wxi[r] = bs2f(vi[r]); wxf[r] = bs2f(vf[r]);
        wxg[r] = bs2f(vg[r]); wxo[r] = bs2f(vo[r]);
      }
      float fsh[4], osh[4];
      #pragma unroll
      for (int r = 0; r < 4; ++r) {
        fsh[r] = __shfl_xor(acc0[r], 32, 64);
        osh[r] = __shfl_xor(acc1[r], 32, 64);
      }

      if (q < 2 && b < 8) {
        short4v hp4; floatx4 hf4, cf4;
        #pragma unroll
        for (int r = 0; r < 4; ++r) {
          const float pi = acc0[r] + wxi[r] + ubi[r];
          const float pf = fsh[r]  + wxf[r] + ubf[r];
          const float pg = acc1[r] + wxg[r] + ubg[r];
          const float po = osh[r]  + wxo[r] + ubo[r];
          const float it = sigm(pi), ft = sigm(pf);
          const float gt = tanhf_(pg), ot = sigm(po);
          const float cv = ft * cst[r] + it * gt;
          cst[r] = cv;
          const float hv = ot * fmaxf(cv, 0.f);
          hf4[r] = hv; cf4[r] = cv; hp4[r] = f2bs(hv);
        }
        union { short4v v; u64 u; } pk; pk.v = hp4;
        cstore(payl0 + (long)t * 1024 + blk * 16 + (b * 2 + (q & 1)), pk.u);
        if (t == T_STEPS - 1) {
          *reinterpret_cast<floatx4*>(hh + b * 512 + jj) = hf4;
          *reinterpret_cast<floatx4*>(cc + b * 512 + jj) = cf4;
        }
      }
    }
  } else {
    // ---- Layer 1: K=1024 ([W1|U1] * [h1(t); h2(t-1)]) ----
    short8 a0[32], a1[32];
    {
      const bf16* W0p = Wb1 + (long)row0 * 512 + q * 8;
      const bf16* W1p = Wb1 + (long)row1 * 512 + q * 8;
      const bf16* U0p = Ub1 + (long)row0 * 512 + q * 8;
      const bf16* U1p = Ub1 + (long)row1 * 512 + q * 8;
      #pragma unroll
      for (int kt = 0; kt < 16; ++kt) {
        a0[kt]      = *reinterpret_cast<const short8*>(W0p + kt * 32);
        a1[kt]      = *reinterpret_cast<const short8*>(W1p + kt * 32);
        a0[16 + kt] = *reinterpret_cast<const short8*>(U0p + kt * 32);
        a1[16 + kt] = *reinterpret_cast<const short8*>(U1p + kt * 32);
      }
    }
    float ubi[4], ubf[4], ubg[4], ubo[4];
    #pragma unroll
    for (int r = 0; r < 4; ++r) {
      ubi[r] = w1b[        jj + r] + u1b[        jj + r];
      ubf[r] = w1b[ 512 + jj + r] + u1b[ 512 + jj + r];
      ubg[r] = w1b[1024 + jj + r] + u1b[1024 + jj + r];
      ubo[r] = w1b[1536 + jj + r] + u1b[1536 + jj + r];
    }
    float cst[4] = {0.f, 0.f, 0.f, 0.f};

    for (int t = 0; t < T_STEPS; ++t) {
      floatx4 acc0 = {0.f, 0.f, 0.f, 0.f};
      floatx4 acc1 = {0.f, 0.f, 0.f, 0.f};

      const u64* p0 = payl0 + (long)t * 1024 + lane * 16;
      u64 w0[16], w1[16];
      int guard = 0;
      if (t > 0) {
        const u64* p1 = payl1 + ((long)(t - 1)) * 1024 + lane * 16;
        for (;;) {
          int ok = 1;
          #pragma unroll
          for (int i = 0; i < 16; ++i) {
            w1[i] = cload(p1 + i);
            ok &= (w1[i] != SENT64);
          }
          #pragma unroll
          for (int i = 0; i < 16; ++i) {
            w0[i] = cload(p0 + i);
            ok &= (w0[i] != SENT64);
          }
          if (__all(ok)) break;
          if (++guard > (1 << 22)) break;
        }
      } else {
        for (;;) {
          int ok = 1;
          #pragma unroll
          for (int i = 0; i < 16; ++i) {
            w0[i] = cload(p0 + i);
            ok &= (w0[i] != SENT64);
          }
          if (__all(ok)) break;
          if (++guard > (1 << 22)) break;
        }
      }
      #pragma unroll
      for (int i = 0; i < 16; ++i) {
        *reinterpret_cast<u64*>(lds + (i >> 1) * STR1 + lane * 16 + (i & 1) * 8) = w0[i];
      }
      if (t > 0) {
        #pragma unroll
        for (int i = 0; i < 16; ++i) {
          *reinterpret_cast<u64*>(lds + (i >> 1) * STR1 + 1024 + lane * 16 + (i & 1) * 8) = w1[i];
        }
      }
      #pragma unroll
      for (int kt = 0; kt < 16; ++kt) {
        short8 hb = *reinterpret_cast<const short8*>(
            lds + (b & 7) * STR1 + kt * 64 + q * 16);
        acc0 = mfma_bf16(a0[kt], hb, acc0);
        acc1 = mfma_bf16(a1[kt], hb, acc1);
      }
      if (t > 0) {
        #pragma unroll
        for (int kt = 16; kt < 32; ++kt) {
          short8 hb = *reinterpret_cast<const short8*>(
              lds + (b & 7) * STR1 + kt * 64 + q * 16);
          acc0 = mfma_bf16(a0[kt], hb, acc0);
          acc1 = mfma_bf16(a1[kt], hb, acc1);
        }
      }

      float fsh[4], osh[4];
      #pragma unroll
      for (int r = 0; r < 4; ++r) {
        fsh[r] = __shfl_xor(acc0[r], 32, 64);
        osh[r] = __shfl_xor(acc1[r], 32, 64);
      }

      if (q < 2 && b < 8) {
        short4v hp4; floatx4 hf4, cf4;
        #pragma unroll
        for (int r = 0; r < 4; ++r) {
          const float pi = acc0[r] + ubi[r];
          const float pf = fsh[r]  + ubf[r];
          const float pg = acc1[r] + ubg[r];
          const float po = osh[r]  + ubo[r];
          const float it = sigm(pi), ft = sigm(pf);
          const float gt = tanhf_(pg), ot = sigm(po);
          const float cv = ft * cst[r] + it * gt;
          cst[r] = cv;
          const float hv = ot * fmaxf(cv, 0.f);
          hf4[r] = hv; cf4[r] = cv; hp4[r] = f2bs(hv);
        }
        union { short4v v; u64 u; } pk; pk.v = hp4;
        cstore(payl1 + (long)t * 1024 + blk * 16 + (b * 2 + (q & 1)), pk.u);
        *reinterpret_cast<floatx4*>(out + (long)b * 1048576 + (long)t * 512 + jj) = hf4;
        if (t == T_STEPS - 1) {
          *reinterpret_cast<floatx4*>(hh + b * 512 + jj) = hf4;
          *reinterpret_cast<floatx4*>(cc + b * 512 + jj) = cf4;
        }
      }
    }
  }

  // Signal heaters to exit.
  if (lane == 0) {
    __hip_atomic_fetch_add(done, 1u, __ATOMIC_RELAXED, __HIP_MEMORY_SCOPE_AGENT);
  }
}

extern "C" void kernel_launch(void* const* d_in, const int* in_sizes, int n_in,
                              void* d_out, int out_size, void* d_ws, size_t ws_size,
                              hipStream_t stream) {
  (void)in_sizes; (void)n_in; (void)out_size; (void)ws_size;
  const float* x   = (const float*)d_in[0];
  const float* w0w = (const float*)d_in[1];
  const float* w0b = (const float*)d_in[2];
  const float* u0w = (const float*)d_in[3];
  const float* u0b = (const float*)d_in[4];
  const float* w1w = (const float*)d_in[5];
  const float* w1b = (const float*)d_in[6];
  const float* u1w = (const float*)d_in[7];
  const float* u1b = (const float*)d_in[8];
  float* out = (float*)d_out;

  char* ws = (char*)d_ws;
  u64*  payl0 = (u64*)ws;
  u64*  payl1 = (u64*)(ws + (size_t)16777216);
  bf16* Wb0 = (bf16*)(ws + (size_t)33554432);
  bf16* Ub0 = (bf16*)(ws + (size_t)34603008);
  bf16* Wb1 = (bf16*)(ws + (size_t)36700160);
  bf16* Ub1 = (bf16*)(ws + (size_t)38797312);
  bf16* wx  = (bf16*)(ws + (size_t)40894464);
  unsigned int* done = (unsigned int*)(ws + (size_t)115343360);

  // Sentinel-fill payload arrays; zero the done counter.
  hipMemsetAsync(ws, 0xFF, (size_t)33554432, stream);
  hipMemsetAsync(done, 0, 64, stream);

  // Weight conversions fp32 -> bf16.
  cvt_f32_bf16<<<512,  256, 0, stream>>>(w0w, Wb0, 524288);
  cvt_f32_bf16<<<1024, 256, 0, stream>>>(u0w, Ub0, 1048576);
  cvt_f32_bf16<<<1024, 256, 0, stream>>>(w1w, Wb1, 1048576);
  cvt_f32_bf16<<<1024, 256, 0, stream>>>(u1w, Ub1, 1048576);

  // Layer-0 input projection.
  dim3 gg(1024, 8, 1);
  gemm_proj<<<gg, 256, 0, stream>>>(x, Wb0, w0b, wx, 256, 2048 * 256, 256);

  // Fused 2-layer recurrence + heaters.
  lstm_fused<<<N_BLK, 256, 0, stream>>>(wx, Ub0, Wb1, Ub1, u0b, w1b, u1b,
                                        out, payl0, payl1, done);
}